// Round 16
// baseline (40.575 us; speedup 1.0000x reference)
//
#include <hip/hip_runtime.h>

// CharacterCNN — DEDUPE-BY-12-BIT-KEY, fully fused, 2 dispatches.
// out[token] = F(key), key = m3i:8 | st1:1 | st2:1 | st19:1 | st20:1.
//  K1 fused_ucompute (256 blocks, 16 keys each): build conv tables in LDS
//     from E/W/b; phase-1 gather from LDS tables; highway MFMA reading
//     Ht/Hg f32 directly (in-register f16 convert); projection (P hi+lo
//     in-register) -> uout[4096][64] f32.
//  K2 keyscatter (n_tok/64 blocks): 64 threads compute keys -> LDS;
//     256 threads gather uout rows and write out fully coalesced.

typedef _Float16 f16;
typedef __attribute__((ext_vector_type(8))) _Float16 f16x8;
typedef __attribute__((ext_vector_type(4))) float f32x4;

// ---- table offsets inside LDS tab (f16 units) ----
#define LC1   0
#define LRAW2 96
#define LT2   672
#define LRAW3 1696
#define LT3LO 5152
#define LT3HI 7200
#define TABSZ 9248
#define NKEYS 4096
#define CROW  232
#define UOUT_OFF 0        // ws: f32[4096*64] = 1 MB

__device__ __forceinline__ f16x8 hmax8(f16x8 a, f16x8 b) {
  return __builtin_elementwise_max(a, b);
}

__device__ __forceinline__ f16x8 pin8(f16x8 v) {
  union { f16x8 v; unsigned w[4]; } x; x.v = v;
  asm volatile("" : "+v"(x.w[0]), "+v"(x.w[1]), "+v"(x.w[2]), "+v"(x.w[3]) :: "memory");
  return x.v;
}

// load 8 consecutive f32, convert to f16x8 (RTN)
__device__ __forceinline__ f16x8 ldcvt(const float* __restrict__ p) {
  float4 a = *(const float4*)p;
  float4 b = *(const float4*)(p + 4);
  f16x8 r;
  r[0] = (f16)a.x; r[1] = (f16)a.y; r[2] = (f16)a.z; r[3] = (f16)a.w;
  r[4] = (f16)b.x; r[5] = (f16)b.y; r[6] = (f16)b.z; r[7] = (f16)b.w;
  return r;
}

// load 8 f32 -> hi/lo f16x8 pair (w = hi + lo)
__device__ __forceinline__ void ldcvt2(const float* __restrict__ p,
                                       f16x8& hi, f16x8& lo) {
  float4 a = *(const float4*)p;
  float4 b = *(const float4*)(p + 4);
  float wv[8] = {a.x, a.y, a.z, a.w, b.x, b.y, b.z, b.w};
#pragma unroll
  for (int j = 0; j < 8; j++) {
    f16 h = (f16)wv[j];
    hi[j] = h;
    lo[j] = (f16)(wv[j] - (float)h);
  }
}

// ---------------- K1: fused ucompute (no prep dependency) ----------------
__global__ __launch_bounds__(256) void fused_ucompute(
    const float* __restrict__ E,
    const float* __restrict__ W1, const float* __restrict__ b1,
    const float* __restrict__ W2, const float* __restrict__ b2,
    const float* __restrict__ W3, const float* __restrict__ b3,
    const float* __restrict__ HtW, const float* __restrict__ HgW,
    const float* __restrict__ PW,
    const float* __restrict__ Htb, const float* __restrict__ Hgb,
    const float* __restrict__ Pb, float* __restrict__ uout)
{
  __shared__ float X[3][16];
  __shared__ float U1[3][32];
  __shared__ float U2[9][64];
  __shared__ float U3[27][128];
  __shared__ __attribute__((aligned(16))) f16 tab[TABSZ];
  __shared__ __attribute__((aligned(16))) f16 cnn[16 * CROW];

  const int tid = threadIdx.x;
  const int wave = tid >> 6, lane = tid & 63;
  const int kbase = blockIdx.x * 16;
  const int lrow = lane & 15;
  const int kg8 = (lane >> 4) * 8;
  const int rr0 = (lane >> 4) * 4;

  // ---- stage 0: conv pattern values U (f32, exact) ----
  if (tid < 48) { int s = tid >> 4, i = tid & 15; X[s][i] = (s == 0) ? 0.f : E[(s - 1) * 16 + i]; }
  __syncthreads();
  for (int idx = tid; idx < 96; idx += 256) {
    int s = idx >> 5, c = idx & 31;
    float acc = b1[c];
#pragma unroll
    for (int i = 0; i < 16; i++) acc += W1[c * 16 + i] * X[s][i];
    U1[s][c] = acc;
  }
  for (int idx = tid; idx < 576; idx += 256) {
    int p = idx >> 6, c = idx & 63;
    int sa = p / 3, sb = p % 3;
    float acc = b2[c];
#pragma unroll
    for (int i = 0; i < 16; i++)
      acc += W2[c * 32 + i * 2 + 0] * X[sa][i] + W2[c * 32 + i * 2 + 1] * X[sb][i];
    U2[p][c] = acc;
  }
  for (int idx = tid; idx < 3456; idx += 256) {
    int p = idx >> 7, c = idx & 127;
    int sa = p / 9, sb = (p / 3) % 3, sc = p % 3;
    float acc = b3[c];
#pragma unroll
    for (int i = 0; i < 16; i++)
      acc += W3[c * 48 + i * 3 + 0] * X[sa][i]
           + W3[c * 48 + i * 3 + 1] * X[sb][i]
           + W3[c * 48 + i * 3 + 2] * X[sc][i];
    U3[p][c] = acc;
  }
  __syncthreads();

  // ---- stage 1: f16 tables (raw rows + interior subset-max) ----
  if (tid < 96) {
    int r = tid >> 5, c = tid & 31;
    float v = (r == 0) ? fmaxf(U1[1][c], U1[2][c]) : U1[r][c];
    tab[LC1 + tid] = (f16)v;
  }
  for (int idx = tid; idx < 576; idx += 256) tab[LRAW2 + idx] = (f16)U2[idx >> 6][idx & 63];
  for (int idx = tid; idx < 3456; idx += 256) tab[LRAW3 + idx] = (f16)U3[idx >> 7][idx & 127];
  for (int idx = tid; idx < 1024; idx += 256) {   // T2 subsets: bit b -> (1+(b>>1), 1+(b&1))
    int s = idx >> 6, c = idx & 63;
    float m = -65504.f;
#pragma unroll
    for (int b = 0; b < 4; b++)
      if ((s >> b) & 1) m = fmaxf(m, U2[4 + 3 * (b >> 1) + (b & 1)][c]);
    tab[LT2 + idx] = (f16)m;
  }
  for (int idx = tid; idx < 2048; idx += 256) {   // T3lo (a=1), T3hi (a=2)
    int s = idx >> 7, c = idx & 127;
    float m = -65504.f;
#pragma unroll
    for (int b = 0; b < 4; b++)
      if ((s >> b) & 1) m = fmaxf(m, U3[13 + 3 * (b >> 1) + (b & 1)][c]);
    tab[LT3LO + idx] = (f16)m;
    m = -65504.f;
#pragma unroll
    for (int b = 0; b < 4; b++)
      if ((s >> b) & 1) m = fmaxf(m, U3[22 + 3 * (b >> 1) + (b & 1)][c]);
    tab[LT3HI + idx] = (f16)m;
  }
  __syncthreads();

  // ---- masks derived per-thread from key = kbase + (tid>>4) ----
  const int p1row = tid >> 4;
  const int p1g = tid & 15;
  unsigned mw, mb;
  {
    unsigned key = (unsigned)(kbase + p1row);
    unsigned m3i = key & 255u;
    int st1 = 1 + (int)((key >> 8) & 1),  st2 = 1 + (int)((key >> 9) & 1);
    int st19 = 1 + (int)((key >> 10) & 1), st20 = 1 + (int)((key >> 11) & 1);
    unsigned m2i = 0, mchar = 0;
#pragma unroll
    for (int p = 0; p < 8; p++)
      if ((m3i >> p) & 1) {
        m2i |= (1u << (p >> 1)) | (1u << (p & 3));
        mchar |= (1u << ((p >> 2) & 1)) | (1u << ((p >> 1) & 1)) | (1u << (p & 1));
      }
    unsigned sel = (mchar == 3u) ? 0u : ((mchar & 1u) ? 1u : 2u);
    mw = m3i | (m2i << 8) | (sel << 12);
    mb = (unsigned)st1 | ((unsigned)(st20 * 3) << 4)
       | ((unsigned)(st1 * 3 + st2) << 8) | ((unsigned)(st19 * 9 + st20 * 3) << 16);
  }

  // ---- phase 1: conv max from LDS tables; ReLU clamp ----
  const f16x8 KZ = {0, 0, 0, 0, 0, 0, 0, 0};
  {
    const int m3 = mw & 255;
    f16x8 v = hmax8(*(const f16x8*)&tab[LT3LO + (m3 & 15) * 128 + p1g * 8],
                    *(const f16x8*)&tab[LT3HI + ((m3 >> 4) & 15) * 128 + p1g * 8]);
    v = hmax8(v, *(const f16x8*)&tab[LRAW3 + ((mb >> 8) & 15) * 128 + p1g * 8]);
    v = hmax8(v, *(const f16x8*)&tab[LRAW3 + ((mb >> 16) & 31) * 128 + p1g * 8]);
    *(f16x8*)&cnn[p1row * CROW + 96 + p1g * 8] = hmax8(v, KZ);
    if (p1g < 8) {
      f16x8 u = *(const f16x8*)&tab[LT2 + ((mw >> 8) & 15) * 64 + p1g * 8];
      u = hmax8(u, *(const f16x8*)&tab[LRAW2 + (mb & 15) * 64 + p1g * 8]);
      u = hmax8(u, *(const f16x8*)&tab[LRAW2 + ((mb >> 4) & 15) * 64 + p1g * 8]);
      *(f16x8*)&cnn[p1row * CROW + 32 + p1g * 8] = hmax8(u, KZ);
    }
    if (p1g < 4) {
      int sel = (mw >> 12) & 3;
      f16x8 w = *(const f16x8*)&tab[LC1 + sel * 32 + p1g * 8];
      *(f16x8*)&cnn[p1row * CROW + p1g * 8] = hmax8(w, KZ);
    }
  }
  __syncthreads();

  // ---- A-fragments ----
  f16x8 af[7];
#pragma unroll
  for (int kf = 0; kf < 7; kf++)
    af[kf] = *(const f16x8*)&cnn[lrow * CROW + kf * 32 + kg8];
#pragma unroll
  for (int kf = 0; kf < 7; kf++) af[kf] = pin8(af[kf]);
  __syncthreads();   // all waves captured af before in-place hw writes

  // ---- highway: wave w -> nf = w, w+4, w+8, w+12(w<2); f32 weights direct ----
  const int nf_cnt = (wave < 2) ? 4 : 3;
  for (int i = 0; i < nf_cnt; i++) {
    const int nf = wave + i * 4;
    const int col = nf * 16 + lrow;
    const float* wt = HtW + (size_t)col * 224 + kg8;
    const float* wg = HgW + (size_t)col * 224 + kg8;
    const float bt = Htb[col], bg = Hgb[col];
    f32x4 aT = {bt, bt, bt, bt};
    f32x4 aG = {bg, bg, bg, bg};
#pragma unroll
    for (int kf = 0; kf < 7; kf++) {
      f16x8 wTv = ldcvt(wt + kf * 32);
      f16x8 wGv = ldcvt(wg + kf * 32);
      aT = __builtin_amdgcn_mfma_f32_16x16x32_f16(af[kf], wTv, aT, 0, 0, 0);
      aG = __builtin_amdgcn_mfma_f32_16x16x32_f16(af[kf], wGv, aG, 0, 0, 0);
    }
#pragma unroll
    for (int r = 0; r < 4; r++) {
      int row = rr0 + r;
      float t  = fmaxf(aT[r], 0.f);
      float gg = __builtin_amdgcn_rcpf(1.f + __expf(-aG[r]));
      float cv = (float)cnn[row * CROW + col];
      cnn[row * CROW + col] = (f16)(cv + gg * (t - cv));   // own cols only
    }
  }
  __syncthreads();   // hw complete before projection reads all cols

  // ---- projection: wave w -> nf = w; P hi+lo in-register ----
  f16x8 ah[7];
#pragma unroll
  for (int kf = 0; kf < 7; kf++)
    ah[kf] = *(const f16x8*)&cnn[lrow * CROW + kf * 32 + kg8];
  {
    const int col = wave * 16 + lrow;
    const float* pw = PW + (size_t)col * 224 + kg8;
    const float bp = Pb[col];
    f32x4 ac = {bp, bp, bp, bp};
#pragma unroll
    for (int kf = 0; kf < 7; kf++) {
      f16x8 wh, wl;
      ldcvt2(pw + kf * 32, wh, wl);
      ac = __builtin_amdgcn_mfma_f32_16x16x32_f16(ah[kf], wh, ac, 0, 0, 0);
      ac = __builtin_amdgcn_mfma_f32_16x16x32_f16(ah[kf], wl, ac, 0, 0, 0);
    }
#pragma unroll
    for (int r = 0; r < 4; r++)
      uout[(size_t)(kbase + rr0 + r) * 64 + col] = ac[r];
  }
}

// ---------------- K2: key + scatter (coalesced) ----------------
__global__ __launch_bounds__(256) void keyscatter_kernel(
    const int* __restrict__ ids, const float* __restrict__ uout,
    float* __restrict__ out, int n_tok)
{
  __shared__ unsigned keys[64];
  const int tid = threadIdx.x;
  const int tok0 = blockIdx.x * 64;

  if (tid < 64) {
    unsigned key = 0;
    int t = tok0 + tid;
    if (t < n_tok) {
      const int4* idp4 = (const int4*)(ids + (size_t)t * 20);
      int st[21];
#pragma unroll
      for (int q = 0; q < 5; q++) {
        int4 v = idp4[q];
        st[q * 4 + 1] = v.x; st[q * 4 + 2] = v.y;   // raw 0/1
        st[q * 4 + 3] = v.z; st[q * 4 + 4] = v.w;
      }
      unsigned m3i = 0;
#pragma unroll
      for (int l = 1; l <= 18; l++)
        m3i |= 1u << ((st[l] << 2) | (st[l + 1] << 1) | st[l + 2]);
      key = m3i | ((unsigned)st[1] << 8) | ((unsigned)st[2] << 9)
          | ((unsigned)st[19] << 10) | ((unsigned)st[20] << 11);
    }
    keys[tid] = key;
  }
  __syncthreads();

  const int tl = tid >> 2, q = tid & 3;
  const int t = tok0 + tl;
  if (t >= n_tok) return;
  const float4* src = (const float4*)(uout + (size_t)keys[tl] * 64 + q * 16);
  float4* dst = (float4*)(out + (size_t)t * 64 + q * 16);
  dst[0] = src[0]; dst[1] = src[1]; dst[2] = src[2]; dst[3] = src[3];
}

extern "C" void kernel_launch(void* const* d_in, const int* in_sizes, int n_in,
                              void* d_out, int out_size, void* d_ws, size_t ws_size,
                              hipStream_t stream) {
  const int*   ids = (const int*)d_in[0];
  const float* E   = (const float*)d_in[1];
  const float* W1  = (const float*)d_in[2];
  const float* b1  = (const float*)d_in[3];
  const float* W2  = (const float*)d_in[4];
  const float* b2  = (const float*)d_in[5];
  const float* W3  = (const float*)d_in[6];
  const float* b3  = (const float*)d_in[7];
  const float* HtW = (const float*)d_in[8];
  const float* Htb = (const float*)d_in[9];
  const float* HgW = (const float*)d_in[10];
  const float* Hgb = (const float*)d_in[11];
  const float* PW  = (const float*)d_in[12];
  const float* Pb  = (const float*)d_in[13];
  float* out = (float*)d_out;
  float* uout = (float*)((char*)d_ws + UOUT_OFF);

  const int n_tok = in_sizes[0] / 20;
  fused_ucompute<<<NKEYS / 16, 256, 0, stream>>>(
      E, W1, b1, W2, b2, W3, b3, HtW, HgW, PW, Htb, Hgb, Pb, uout);
  keyscatter_kernel<<<(n_tok + 63) / 64, 256, 0, stream>>>(ids, uout, out, n_tok);
}